// Round 1
// baseline (791.239 us; speedup 1.0000x reference)
//
#include <hip/hip_runtime.h>

#define SEQ   512
#define BATCH 256
#define INDIM 784
#define HID   10
#define NC4   196   // INDIM / 4

// ---------------------------------------------------------------------------
// Kernel 1: xi[t][b][j] = sum_i x[t][b][i] * W_ih[j][i] + b_ih[j] + b_hh[j]
// One wave per row (row = t*BATCH + b). Lanes span the contiguous 784-dim
// (coalesced float4 loads), W_ih staged in LDS, butterfly reduction.
// ---------------------------------------------------------------------------
__global__ __launch_bounds__(256) void xproj_kernel(
    const float* __restrict__ x, const float* __restrict__ Wih,
    const float* __restrict__ bih, const float* __restrict__ bhh,
    float* __restrict__ xi)
{
    __shared__ float4 ldsW[HID * NC4];   // 31,360 B
    {
        const float4* W4 = (const float4*)Wih;
        for (int p = threadIdx.x; p < HID * NC4; p += 256) ldsW[p] = W4[p];
    }
    __syncthreads();

    const int lane = threadIdx.x & 63;
    const int wave = threadIdx.x >> 6;

    float bias[HID];
#pragma unroll
    for (int j = 0; j < HID; ++j) bias[j] = bih[j] + bhh[j];

    const float4* x4 = (const float4*)x;
    const int rowBase = blockIdx.x * 64 + wave * 16;

    for (int rr = 0; rr < 16; ++rr) {
        const int row = rowBase + rr;
        const float4* xr = x4 + (long)row * NC4;

        float acc[HID];
#pragma unroll
        for (int j = 0; j < HID; ++j) acc[j] = 0.f;

#pragma unroll
        for (int k = 0; k < 3; ++k) {
            float4 xv = xr[k * 64 + lane];
#pragma unroll
            for (int j = 0; j < HID; ++j) {
                float4 wv = ldsW[j * NC4 + k * 64 + lane];
                acc[j] = fmaf(xv.x, wv.x, acc[j]);
                acc[j] = fmaf(xv.y, wv.y, acc[j]);
                acc[j] = fmaf(xv.z, wv.z, acc[j]);
                acc[j] = fmaf(xv.w, wv.w, acc[j]);
            }
        }
        // remainder: 196 = 3*64 + 4 float4 columns
        if (lane < 4) {
            float4 xv = xr[192 + lane];
#pragma unroll
            for (int j = 0; j < HID; ++j) {
                float4 wv = ldsW[j * NC4 + 192 + lane];
                acc[j] = fmaf(xv.x, wv.x, acc[j]);
                acc[j] = fmaf(xv.y, wv.y, acc[j]);
                acc[j] = fmaf(xv.z, wv.z, acc[j]);
                acc[j] = fmaf(xv.w, wv.w, acc[j]);
            }
        }

        // full 64-lane butterfly reduce (all lanes end with total)
#pragma unroll
        for (int off = 1; off < 64; off <<= 1) {
#pragma unroll
            for (int j = 0; j < HID; ++j) acc[j] += __shfl_xor(acc[j], off, 64);
        }

        if (lane == 0) {
            float2* po = (float2*)(xi + (long)row * HID);
            po[0] = make_float2(acc[0] + bias[0], acc[1] + bias[1]);
            po[1] = make_float2(acc[2] + bias[2], acc[3] + bias[3]);
            po[2] = make_float2(acc[4] + bias[4], acc[5] + bias[5]);
            po[3] = make_float2(acc[6] + bias[6], acc[7] + bias[7]);
            po[4] = make_float2(acc[8] + bias[8], acc[9] + bias[9]);
        }
    }
}

// ---------------------------------------------------------------------------
// Kernel 2: sequential scan h_t = relu(xi_t + h_{t-1} @ W_hh^T)
// Batch elements are independent -> 2 threads per batch element (xor-1 pair
// in the same wave), each owns 5 of the 10 hidden dims. W_hh columns are
// permuted per-thread at load so that h[0..4]=my dims, h[5..9]=partner dims:
// no runtime register indexing, no cndmask in the hot loop.
// ---------------------------------------------------------------------------
__global__ __launch_bounds__(256) void scan_kernel(
    const float* __restrict__ xi, const float* __restrict__ Whh,
    float* __restrict__ out)
{
    const int gid  = blockIdx.x * 256 + threadIdx.x;   // 0..511
    const int b    = gid >> 1;
    const int half = gid & 1;
    const int j0   = half * 5;                          // my dims: [j0, j0+5)

    // W[jj][k]: row j0+jj of W_hh, columns permuted: k<5 -> my dim k+j0,
    // k>=5 -> partner dim (k-5)+(5-j0) == k-j0.
    float W[5][10];
#pragma unroll
    for (int jj = 0; jj < 5; ++jj)
#pragma unroll
        for (int k = 0; k < 10; ++k) {
            const int col = (k < 5) ? (k + j0) : (k - j0);
            W[jj][k] = Whh[(j0 + jj) * HID + col];
        }

    float h[10];
#pragma unroll
    for (int k = 0; k < 10; ++k) h[k] = 0.f;

    const float* xib  = xi  + b * HID + j0;
    float*       outb = out + b * HID + j0;

    float cur[5];
#pragma unroll
    for (int jj = 0; jj < 5; ++jj) cur[jj] = xib[jj];

    for (int t = 0; t < SEQ; ++t) {
        // prefetch next timestep's xi while this step computes
        float nx[5];
        if (t + 1 < SEQ) {
            const float* p = xib + (long)(t + 1) * BATCH * HID;
#pragma unroll
            for (int jj = 0; jj < 5; ++jj) nx[jj] = p[jj];
        }

        float s[5];
#pragma unroll
        for (int jj = 0; jj < 5; ++jj) {
            float a = cur[jj];
#pragma unroll
            for (int k = 0; k < 10; ++k) a = fmaf(W[jj][k], h[k], a);
            s[jj] = fmaxf(a, 0.f);
        }

        float* po = outb + (long)t * BATCH * HID;
#pragma unroll
        for (int jj = 0; jj < 5; ++jj) po[jj] = s[jj];

#pragma unroll
        for (int jj = 0; jj < 5; ++jj) {
            h[jj]     = s[jj];
            h[5 + jj] = __shfl_xor(s[jj], 1, 64);
        }
#pragma unroll
        for (int jj = 0; jj < 5; ++jj) cur[jj] = nx[jj];
    }

    // h_last: appended after out[S,B,H] in d_out
    float* pl = out + (long)SEQ * BATCH * HID + b * HID + j0;
#pragma unroll
    for (int jj = 0; jj < 5; ++jj) pl[jj] = h[jj];
}

// ---------------------------------------------------------------------------
extern "C" void kernel_launch(void* const* d_in, const int* in_sizes, int n_in,
                              void* d_out, int out_size, void* d_ws, size_t ws_size,
                              hipStream_t stream)
{
    const float* x   = (const float*)d_in[0];
    const float* Wih = (const float*)d_in[1];
    const float* Whh = (const float*)d_in[2];
    const float* bih = (const float*)d_in[3];
    const float* bhh = (const float*)d_in[4];
    float* out = (float*)d_out;
    float* xi  = (float*)d_ws;   // SEQ*BATCH*HID floats = 5.24 MB

    // 131072 rows / 64 rows per block = 2048 blocks
    xproj_kernel<<<2048, 256, 0, stream>>>(x, Wih, bih, bhh, xi);
    scan_kernel<<<2, 256, 0, stream>>>(xi, Whh, out);
}

// Round 2
// 703.040 us; speedup vs baseline: 1.1255x; 1.1255x over previous
//
#include <hip/hip_runtime.h>

#define SEQ   512
#define BATCH 256
#define INDIM 784
#define HID   10
#define NC4   196   // INDIM / 4
#define CHUNK 56    // columns staged per iteration (784 = 14 * 56)
#define NCH   14
#define STR   257   // LDS row stride in floats (odd -> <=2-way bank aliasing)

// ---------------------------------------------------------------------------
// Kernel 1: xi[row][j] = x[row] . W_ih[j] + b_ih[j] + b_hh[j],  row = t*B+b
// Lane-per-row: block of 256 threads owns 256 rows. x is staged through LDS
// TRANSPOSED (lds[c][r]) in CHUNK-column slabs so the compute-phase read
// lds[c*STR + tid] is conflict-free (stride-1 across lanes) and the write
// (4c+k)*STR + r with odd STR is <=2-way (free). W is read with wave-uniform
// indices -> scalar loads on the SMEM pipe, leaving LDS/VALU clean.
// Next chunk is prefetched into registers to overlap global latency.
// ---------------------------------------------------------------------------
__global__ __launch_bounds__(256) void xproj_kernel(
    const float* __restrict__ x, const float* __restrict__ Wih,
    const float* __restrict__ bih, const float* __restrict__ bhh,
    float* __restrict__ xi)
{
    __shared__ float lds[CHUNK * STR];   // 57,568 B -> 2 blocks/CU

    const int tid  = threadIdx.x;
    const long row0 = (long)blockIdx.x * 256;
    const float4* x4 = (const float4*)x + row0 * NC4;

    float acc[HID];
#pragma unroll
    for (int j = 0; j < HID; ++j) acc[j] = bih[j] + bhh[j];

    float4 stg[14];
    // preload chunk 0: 256 rows x 14 float4, coalesced (c4 fastest)
#pragma unroll
    for (int k = 0; k < 14; ++k) {
        const int idx = k * 256 + tid;
        const int c4 = idx % 14, r = idx / 14;
        stg[k] = x4[(long)r * NC4 + c4];
    }

    for (int ch = 0; ch < NCH; ++ch) {
        // staged regs -> LDS, transposed
#pragma unroll
        for (int k = 0; k < 14; ++k) {
            const int idx = k * 256 + tid;
            const int c4 = idx % 14, r = idx / 14;
            const int cb = c4 * 4;
            lds[(cb + 0) * STR + r] = stg[k].x;
            lds[(cb + 1) * STR + r] = stg[k].y;
            lds[(cb + 2) * STR + r] = stg[k].z;
            lds[(cb + 3) * STR + r] = stg[k].w;
        }
        __syncthreads();

        // prefetch next chunk while computing this one
        if (ch + 1 < NCH) {
#pragma unroll
            for (int k = 0; k < 14; ++k) {
                const int idx = k * 256 + tid;
                const int c4 = idx % 14, r = idx / 14;
                stg[k] = x4[(long)r * NC4 + (ch + 1) * 14 + c4];
            }
        }

        const float* wch = Wih + ch * CHUNK;
#pragma unroll 4
        for (int c = 0; c < CHUNK; ++c) {
            const float xv = lds[c * STR + tid];
#pragma unroll
            for (int j = 0; j < HID; ++j)
                acc[j] = fmaf(xv, wch[j * INDIM + c], acc[j]);
        }
        __syncthreads();
    }

    float* po = xi + (row0 + tid) * HID;
#pragma unroll
    for (int j = 0; j < HID; ++j) po[j] = acc[j];
}

// ---------------------------------------------------------------------------
// Kernel 2: h_t = relu(xi_t + h_{t-1} @ W_hh^T). 2 threads per batch element
// (xor-1 pair in-wave), each owns 5 hidden dims; W columns permuted per
// thread so no runtime register indexing. Dot split into two 5-deep fma
// chains (+1 add) to shorten the per-step critical path. 8 blocks x 64
// threads: one wave per CU -> no LDS-pipe contention on the swizzles.
// ---------------------------------------------------------------------------
__global__ __launch_bounds__(64) void scan_kernel(
    const float* __restrict__ xi, const float* __restrict__ Whh,
    float* __restrict__ out)
{
    const int gid  = blockIdx.x * 64 + threadIdx.x;    // 0..511
    const int b    = gid >> 1;
    const int half = gid & 1;
    const int j0   = half * 5;

    // W[jj][k]: row j0+jj, columns permuted: k<5 -> dim k+j0, k>=5 -> k-j0
    float W[5][10];
#pragma unroll
    for (int jj = 0; jj < 5; ++jj)
#pragma unroll
        for (int k = 0; k < 10; ++k) {
            const int col = (k < 5) ? (k + j0) : (k - j0);
            W[jj][k] = Whh[(j0 + jj) * HID + col];
        }

    float h[10];
#pragma unroll
    for (int k = 0; k < 10; ++k) h[k] = 0.f;

    const float* xib  = xi  + b * HID + j0;
    float*       outb = out + b * HID + j0;

    float cur[5];
#pragma unroll
    for (int jj = 0; jj < 5; ++jj) cur[jj] = xib[jj];

    for (int t = 0; t < SEQ; ++t) {
        float nx[5];
        if (t + 1 < SEQ) {
            const float* p = xib + (long)(t + 1) * BATCH * HID;
#pragma unroll
            for (int jj = 0; jj < 5; ++jj) nx[jj] = p[jj];
        }

        float s[5];
#pragma unroll
        for (int jj = 0; jj < 5; ++jj) {
            float a0 = cur[jj];
            float a1 = W[jj][5] * h[5];
#pragma unroll
            for (int k = 0; k < 5; ++k) a0 = fmaf(W[jj][k], h[k], a0);
#pragma unroll
            for (int k = 6; k < 10; ++k) a1 = fmaf(W[jj][k], h[k], a1);
            s[jj] = fmaxf(a0 + a1, 0.f);
        }

        float* po = outb + (long)t * BATCH * HID;
#pragma unroll
        for (int jj = 0; jj < 5; ++jj) po[jj] = s[jj];

#pragma unroll
        for (int jj = 0; jj < 5; ++jj) {
            h[jj]     = s[jj];
            h[5 + jj] = __shfl_xor(s[jj], 1, 64);
        }
#pragma unroll
        for (int jj = 0; jj < 5; ++jj) cur[jj] = nx[jj];
    }

    float* pl = out + (long)SEQ * BATCH * HID + b * HID + j0;
#pragma unroll
    for (int jj = 0; jj < 5; ++jj) pl[jj] = h[jj];
}

// ---------------------------------------------------------------------------
extern "C" void kernel_launch(void* const* d_in, const int* in_sizes, int n_in,
                              void* d_out, int out_size, void* d_ws, size_t ws_size,
                              hipStream_t stream)
{
    const float* x   = (const float*)d_in[0];
    const float* Wih = (const float*)d_in[1];
    const float* Whh = (const float*)d_in[2];
    const float* bih = (const float*)d_in[3];
    const float* bhh = (const float*)d_in[4];
    float* out = (float*)d_out;
    float* xi  = (float*)d_ws;   // SEQ*BATCH*HID floats = 5.24 MB

    xproj_kernel<<<512, 256, 0, stream>>>(x, Wih, bih, bhh, xi);
    scan_kernel<<<8, 64, 0, stream>>>(xi, Whh, out);
}